// Round 7
// baseline (787.195 us; speedup 1.0000x reference)
//
#include <hip/hip_runtime.h>
#include <math.h>

#define B_   2
#define T_   2048
#define C_   1024
#define H_   16
#define HD_  64
#define M_   (B_ * T_)   // 4096

typedef __attribute__((ext_vector_type(8))) short short8;
typedef __attribute__((ext_vector_type(4))) float floatx4;
typedef __attribute__((ext_vector_type(8))) unsigned short ushort8v;

#define WAITV(N) asm volatile("s_waitcnt vmcnt(" #N ")" ::: "memory")
#define SB0()    __builtin_amdgcn_sched_barrier(0)

// split fp32 -> bf16 hi (RNE) + bf16 lo (RNE of remainder)
__device__ __forceinline__ void splitf(float x, unsigned short& h, unsigned short& l) {
    unsigned u  = __float_as_uint(x);
    unsigned hr = (u + 0x7fffu + ((u >> 16) & 1u)) >> 16;
    h = (unsigned short)hr;
    float r = x - __uint_as_float(hr << 16);
    unsigned ur = __float_as_uint(r);
    l = (unsigned short)((ur + 0x7fffu + ((ur >> 16) & 1u)) >> 16);
}

__device__ __forceinline__ void gload16(const void* g, void* l) {
    __builtin_amdgcn_global_load_lds(
        (const __attribute__((address_space(1))) unsigned int*)g,
        (__attribute__((address_space(3))) unsigned int*)l, 16, 0, 0);
}

__device__ __forceinline__ float gelu_f(float x) {
    const float c = 0.7978845608028654f;  // sqrt(2/pi)
    float x3 = x * x * x;
    return 0.5f * x * (1.0f + tanhf(c * (x + 0.044715f * x3)));
}

// ---------------------------------------------------------------------------
// LayerNorm: one block per row, outputs hi/lo bf16.
// ---------------------------------------------------------------------------
__global__ __launch_bounds__(256) void ln_kernel(const float* __restrict__ x,
                                                 const float* __restrict__ w,
                                                 const float* __restrict__ b,
                                                 unsigned short* __restrict__ oh,
                                                 unsigned short* __restrict__ ol) {
    int row = blockIdx.x;
    int t   = threadIdx.x;
    const float4* xr = (const float4*)(x + (size_t)row * C_);
    float4 v = xr[t];
    float s  = v.x + v.y + v.z + v.w;
    float sq = v.x * v.x + v.y * v.y + v.z * v.z + v.w * v.w;
#pragma unroll
    for (int off = 32; off > 0; off >>= 1) {
        s  += __shfl_down(s,  off);
        sq += __shfl_down(sq, off);
    }
    __shared__ float ss[4], ssq[4];
    int wid = t >> 6, lane = t & 63;
    if (lane == 0) { ss[wid] = s; ssq[wid] = sq; }
    __syncthreads();
    float S  = ss[0] + ss[1] + ss[2] + ss[3];
    float SQ = ssq[0] + ssq[1] + ssq[2] + ssq[3];
    float mu   = S * (1.0f / C_);
    float var  = SQ * (1.0f / C_) - mu * mu;
    float rstd = rsqrtf(var + 1e-5f);
    float4 wv = ((const float4*)w)[t];
    float4 bv = ((const float4*)b)[t];
    float o0 = (v.x - mu) * rstd * wv.x + bv.x;
    float o1 = (v.y - mu) * rstd * wv.y + bv.y;
    float o2 = (v.z - mu) * rstd * wv.z + bv.z;
    float o3 = (v.w - mu) * rstd * wv.w + bv.w;
    ushort4 hv, lv;
    splitf(o0, hv.x, lv.x); splitf(o1, hv.y, lv.y);
    splitf(o2, hv.z, lv.z); splitf(o3, hv.w, lv.w);
    *(ushort4*)(oh + (size_t)row * C_ + t * 4) = hv;
    *(ushort4*)(ol + (size_t)row * C_ + t * 4) = lv;
}

// ---------------------------------------------------------------------------
// Weight convert + transpose: W [K][N] f32 -> Wt_hi/lo [N][K] bf16.
// ---------------------------------------------------------------------------
__global__ __launch_bounds__(256) void wtrans_kernel(const float* __restrict__ W,
                                                     unsigned short* __restrict__ th,
                                                     unsigned short* __restrict__ tl,
                                                     int K, int N) {
    __shared__ unsigned int tile[64][65];  // hi | lo<<16
    int n0 = blockIdx.x * 64, k0 = blockIdx.y * 64;
    int t  = threadIdx.x;
    int tc = (t & 15) * 4, tr = t >> 4;
#pragma unroll
    for (int it = 0; it < 4; it++) {
        int kr = it * 16 + tr;
        float4 v = *(const float4*)(W + (size_t)(k0 + kr) * N + n0 + tc);
        unsigned short hh, ll;
        splitf(v.x, hh, ll); tile[kr][tc + 0] = (unsigned)hh | ((unsigned)ll << 16);
        splitf(v.y, hh, ll); tile[kr][tc + 1] = (unsigned)hh | ((unsigned)ll << 16);
        splitf(v.z, hh, ll); tile[kr][tc + 2] = (unsigned)hh | ((unsigned)ll << 16);
        splitf(v.w, hh, ll); tile[kr][tc + 3] = (unsigned)hh | ((unsigned)ll << 16);
    }
    __syncthreads();
    int nl = t >> 2, kc = (t & 3) * 16;
    ushort8v h0, h1, l0, l1;
#pragma unroll
    for (int e = 0; e < 8; e++) {
        unsigned u = tile[kc + e][nl];
        h0[e] = (unsigned short)(u & 0xffff); l0[e] = (unsigned short)(u >> 16);
    }
#pragma unroll
    for (int e = 0; e < 8; e++) {
        unsigned u = tile[kc + 8 + e][nl];
        h1[e] = (unsigned short)(u & 0xffff); l1[e] = (unsigned short)(u >> 16);
    }
    size_t o = (size_t)(n0 + nl) * K + k0 + kc;
    *(ushort8v*)(th + o)     = h0;
    *(ushort8v*)(th + o + 8) = h1;
    *(ushort8v*)(tl + o)     = l0;
    *(ushort8v*)(tl + o + 8) = l1;
}

// ---------------------------------------------------------------------------
// 128x128 split-bf16 MFMA GEMM, 3-buffer counted-vmcnt pipeline.
// Used for proj: C = A@B + R (f32 out). 8 gload16/wave/tile -> vmcnt(8).
// ---------------------------------------------------------------------------
__global__ __launch_bounds__(256) void mfma_gemm_proj(
    const unsigned short* __restrict__ Ah, const unsigned short* __restrict__ Al,
    const unsigned short* __restrict__ Bh, const unsigned short* __restrict__ Bl,
    const float* __restrict__ R, float* __restrict__ Cf,
    int N, int K, int Kstride) {
    __shared__ unsigned short lAh[3][4096], lAl[3][4096];
    __shared__ unsigned short lBh[3][4096], lBl[3][4096];   // 96 KB
    int tid = threadIdx.x, lane = tid & 63, w = tid >> 6;
    int wr = w >> 1, wc = w & 1;

    int nx = gridDim.x;
    int nwg = nx * gridDim.y;
    int bid = blockIdx.y * nx + blockIdx.x;
    int q8  = nwg >> 3;
    int swz = (bid & 7) * q8 + (bid >> 3);
    int bm = (swz / nx) * 128, bn = (swz % nx) * 128;

    int r15 = lane & 15, hq = lane >> 4;

    floatx4 acc[4][4];
#pragma unroll
    for (int i = 0; i < 4; i++)
#pragma unroll
        for (int j = 0; j < 4; j++) acc[i][j] = (floatx4)0.0f;

    auto STAGE = [&](int buf, int k0) {
#pragma unroll
        for (int s = 0; s < 2; s++) {
            int sf = 2 * w + s;
            size_t arow = (size_t)(bm + sf * 16 + r15) * Kstride + k0 + hq * 8;
            size_t brow = (size_t)(bn + sf * 16 + r15) * Kstride + k0 + hq * 8;
            gload16(Ah + arow, &lAh[buf][sf * 512]);
            gload16(Al + arow, &lAl[buf][sf * 512]);
            gload16(Bh + brow, &lBh[buf][sf * 512]);
            gload16(Bl + brow, &lBl[buf][sf * 512]);
        }
    };

    int nt = K / 32;                 // >= 2 for all our shapes
    STAGE(0, 0);
    STAGE(1, 32);
    for (int t = 0; t < nt; t++) {
        if (t + 1 < nt) WAITV(8); else WAITV(0);
        SB0();
        __builtin_amdgcn_s_barrier();
        SB0();
        if (t + 2 < nt) STAGE((t + 2) % 3, (t + 2) * 32);
        int cur = t % 3;
        const short8* fAh = (const short8*)&lAh[cur][0];
        const short8* fAl = (const short8*)&lAl[cur][0];
        const short8* fBh = (const short8*)&lBh[cur][0];
        const short8* fBl = (const short8*)&lBl[cur][0];
        short8 a_h[4], a_l[4], b_h[4], b_l[4];
#pragma unroll
        for (int i = 0; i < 4; i++) {
            a_h[i] = fAh[(wr * 4 + i) * 64 + lane];
            a_l[i] = fAl[(wr * 4 + i) * 64 + lane];
            b_h[i] = fBh[(wc * 4 + i) * 64 + lane];
            b_l[i] = fBl[(wc * 4 + i) * 64 + lane];
        }
        __builtin_amdgcn_s_setprio(1);
#pragma unroll
        for (int i = 0; i < 4; i++)
#pragma unroll
            for (int j = 0; j < 4; j++) {
                acc[i][j] = __builtin_amdgcn_mfma_f32_16x16x32_bf16(a_h[i], b_h[j], acc[i][j], 0, 0, 0);
                acc[i][j] = __builtin_amdgcn_mfma_f32_16x16x32_bf16(a_h[i], b_l[j], acc[i][j], 0, 0, 0);
                acc[i][j] = __builtin_amdgcn_mfma_f32_16x16x32_bf16(a_l[i], b_h[j], acc[i][j], 0, 0, 0);
            }
        __builtin_amdgcn_s_setprio(0);
    }

    int er = hq * 4, ec = r15;
#pragma unroll
    for (int i = 0; i < 4; i++)
#pragma unroll
        for (int j = 0; j < 4; j++) {
            int row0 = bm + wr * 64 + i * 16 + er;
            int col  = bn + wc * 64 + j * 16 + ec;
#pragma unroll
            for (int r = 0; r < 4; r++) {
                int row = row0 + r;
                Cf[(size_t)row * N + col] = acc[i][j][r] + R[(size_t)row * N + col];
            }
        }
}

// ---------------------------------------------------------------------------
// 256x128 split-bf16 MFMA GEMM, 3-buffer counted-vmcnt pipeline, 8 waves
// (2M x 4N, 128x32 each), BK=32, 144 KB LDS. 6 gload16/wave/tile -> vmcnt(6).
// EPI: 0 = split-K partial f32; 2 = gelu -> hi/lo bf16; 3 = qkv scatter.
// ---------------------------------------------------------------------------
template <int EPI>
__global__ __launch_bounds__(512) void gemm_px(
    const unsigned short* __restrict__ Ah, const unsigned short* __restrict__ Al,
    const unsigned short* __restrict__ Bh, const unsigned short* __restrict__ Bl,
    float* __restrict__ Cf,
    unsigned short* __restrict__ Ch, unsigned short* __restrict__ Cl,
    unsigned short* __restrict__ K2h, unsigned short* __restrict__ K2l,
    unsigned short* __restrict__ V2h, unsigned short* __restrict__ V2l,
    int N, int K, int Kstride) {
    __shared__ unsigned short lAh[3][8192], lAl[3][8192];   // 96 KB
    __shared__ unsigned short lBh[3][4096], lBl[3][4096];   // 48 KB
    int tid = threadIdx.x, lane = tid & 63, w = tid >> 6;   // w in 0..7
    int wr = w >> 2, wc = w & 3;                            // 2M x 4N waves

    int nx = gridDim.x;
    int nwg = nx * gridDim.y;
    int bid = blockIdx.y * nx + blockIdx.x;
    int q8  = nwg >> 3;
    int swz = (bid & 7) * q8 + (bid >> 3);
    int bm = (swz / nx) * 256, bn = (swz % nx) * 128;

    int kb = blockIdx.z * K;
    if (EPI == 0) Cf += (size_t)blockIdx.z * (size_t)gridDim.y * 256 * N;

    int r15 = lane & 15, hq = lane >> 4;

    floatx4 acc[8][2];
#pragma unroll
    for (int i = 0; i < 8; i++)
#pragma unroll
        for (int j = 0; j < 2; j++) acc[i][j] = (floatx4)0.0f;

    auto STAGE = [&](int buf, int k0) {
        int sfA0 = 2 * w, sfA1 = 2 * w + 1;     // A: 16 subtiles of 16 rows
        size_t ar0 = (size_t)(bm + sfA0 * 16 + r15) * Kstride + kb + k0 + hq * 8;
        size_t ar1 = (size_t)(bm + sfA1 * 16 + r15) * Kstride + kb + k0 + hq * 8;
        size_t br  = (size_t)(bn + w * 16 + r15) * Kstride + kb + k0 + hq * 8;
        gload16(Ah + ar0, &lAh[buf][sfA0 * 512]);
        gload16(Ah + ar1, &lAh[buf][sfA1 * 512]);
        gload16(Al + ar0, &lAl[buf][sfA0 * 512]);
        gload16(Al + ar1, &lAl[buf][sfA1 * 512]);
        gload16(Bh + br,  &lBh[buf][w * 512]);
        gload16(Bl + br,  &lBl[buf][w * 512]);
    };

    int nt = K / 32;
    STAGE(0, 0);
    STAGE(1, 32);
    for (int t = 0; t < nt; t++) {
        if (t + 1 < nt) WAITV(6); else WAITV(0);
        SB0();
        __builtin_amdgcn_s_barrier();
        SB0();
        if (t + 2 < nt) STAGE((t + 2) % 3, (t + 2) * 32);
        int cur = t % 3;
        const short8* fAh = (const short8*)&lAh[cur][0];
        const short8* fAl = (const short8*)&lAl[cur][0];
        const short8* fBh = (const short8*)&lBh[cur][0];
        const short8* fBl = (const short8*)&lBl[cur][0];
        short8 b_h[2], b_l[2];
#pragma unroll
        for (int j = 0; j < 2; j++) {
            b_h[j] = fBh[(wc * 2 + j) * 64 + lane];
            b_l[j] = fBl[(wc * 2 + j) * 64 + lane];
        }
        __builtin_amdgcn_s_setprio(1);
#pragma unroll
        for (int i = 0; i < 8; i++) {
            short8 a_h = fAh[(wr * 8 + i) * 64 + lane];
            short8 a_l = fAl[(wr * 8 + i) * 64 + lane];
#pragma unroll
            for (int j = 0; j < 2; j++) {
                acc[i][j] = __builtin_amdgcn_mfma_f32_16x16x32_bf16(a_h, b_h[j], acc[i][j], 0, 0, 0);
                acc[i][j] = __builtin_amdgcn_mfma_f32_16x16x32_bf16(a_h, b_l[j], acc[i][j], 0, 0, 0);
                acc[i][j] = __builtin_amdgcn_mfma_f32_16x16x32_bf16(a_l, b_h[j], acc[i][j], 0, 0, 0);
            }
        }
        __builtin_amdgcn_s_setprio(0);
    }

    int er = hq * 4, ec = r15;
#pragma unroll
    for (int i = 0; i < 8; i++) {
#pragma unroll
        for (int j = 0; j < 2; j++) {
            int row0 = bm + wr * 128 + i * 16 + er;
            int col  = bn + wc * 32 + j * 16 + ec;
            if (EPI == 0) {
#pragma unroll
                for (int r = 0; r < 4; r++)
                    Cf[(size_t)(row0 + r) * N + col] = acc[i][j][r];
            } else if (EPI == 2) {
#pragma unroll
                for (int r = 0; r < 4; r++) {
                    int row = row0 + r;
                    float g = gelu_f(acc[i][j][r]);
                    unsigned short hh, ll;
                    splitf(g, hh, ll);
                    Ch[(size_t)row * N + col] = hh;
                    Cl[(size_t)row * N + col] = ll;
                }
            } else {  // EPI == 3: qkv scatter
                int region = bn >> 10;   // uniform per block
                int b_ = row0 >> 11;
                int h_ = (col >> 6) & 15;
                int d_ = col & 63;
                size_t bh_ = (size_t)(b_ * 16 + h_);
                if (region == 2) {
                    ushort4 hv, lv;
                    splitf(acc[i][j][0], hv.x, lv.x);
                    splitf(acc[i][j][1], hv.y, lv.y);
                    splitf(acc[i][j][2], hv.z, lv.z);
                    splitf(acc[i][j][3], hv.w, lv.w);
                    size_t o = (bh_ * 64 + d_) * 2048 + (row0 & 2047);
                    *(ushort4*)(V2h + o) = hv;
                    *(ushort4*)(V2l + o) = lv;
                } else {
                    unsigned short* dh = (region == 0) ? Ch : K2h;
                    unsigned short* dl = (region == 0) ? Cl : K2l;
#pragma unroll
                    for (int r = 0; r < 4; r++) {
                        int t_ = (row0 + r) & 2047;
                        unsigned short hh, ll;
                        splitf(acc[i][j][r], hh, ll);
                        size_t o = (bh_ * 2048 + t_) * 64 + d_;
                        dh[o] = hh;
                        dl[o] = ll;
                    }
                }
            }
        }
    }
}

// ---------------------------------------------------------------------------
// split-K=4 combine: out = p0+p1+p2+p3 + residual
// ---------------------------------------------------------------------------
__global__ __launch_bounds__(256) void combine4_kernel(const float* __restrict__ p0,
                                                       const float* __restrict__ p1,
                                                       const float* __restrict__ p2,
                                                       const float* __restrict__ p3,
                                                       const float* __restrict__ r,
                                                       float* __restrict__ out) {
    int i = blockIdx.x * 256 + threadIdx.x;
    float4 a = ((const float4*)p0)[i];
    float4 b = ((const float4*)p1)[i];
    float4 c = ((const float4*)p2)[i];
    float4 d = ((const float4*)p3)[i];
    float4 e = ((const float4*)r)[i];
    float4 o;
    o.x = a.x + b.x + c.x + d.x + e.x;
    o.y = a.y + b.y + c.y + d.y + e.y;
    o.z = a.z + b.z + c.z + d.z + e.z;
    o.w = a.w + b.w + c.w + d.w + e.w;
    ((float4*)out)[i] = o;
}

// ---------------------------------------------------------------------------
// Split-bf16 MFMA flash attention (causal), work-balanced + pipelined.
// Each block handles TWO Q-tiles of 128 rows: qt = 15-bx (heavy) then bx
// (light) -> uniform 34 KV-iters/block. Grid 8 x 32 = 256 blocks = 1/CU.
// K/V triple-buffered in LDS, counted vmcnt(4), one barrier per KV-iter.
// ---------------------------------------------------------------------------
__global__ __launch_bounds__(512) void attn_mfma(
    const unsigned short* __restrict__ Qh_g, const unsigned short* __restrict__ Ql_g,
    const unsigned short* __restrict__ Kh_g, const unsigned short* __restrict__ Kl_g,
    const unsigned short* __restrict__ Vh_g, const unsigned short* __restrict__ Vl_g,
    unsigned short* __restrict__ yh, unsigned short* __restrict__ yl) {
    __shared__ unsigned short Ks_h[3][4096], Ks_l[3][4096];
    __shared__ unsigned short Vs_h[3][4096], Vs_l[3][4096];   // 96 KB
    __shared__ unsigned short P_s[8][2][1024];                // 32 KB

    int bx  = blockIdx.x;            // 0..7
    int bh  = blockIdx.y;
    int b   = bh >> 4, h = bh & 15;
    int tid = threadIdx.x, lane = tid & 63, w = tid >> 6;
    int r15 = lane & 15, hq = lane >> 4;
    size_t bhq = (size_t)bh * (2048 * 64);
    size_t bhv = (size_t)bh * (64 * 2048);
    int srb = w >> 1, scb = w & 1;

    auto STAGE_KV = [&](int buf, int kt) {
        int k0 = kt * 64;
        size_t koff = bhq + (size_t)(k0 + srb * 16 + r15) * 64 + scb * 32 + hq * 8;
        size_t voff = bhv + (size_t)(srb * 16 + r15) * 2048 + k0 + scb * 32 + hq * 8;
        gload16(Kh_g + koff, &Ks_h[buf][w * 512]);
        gload16(Kl_g + koff, &Ks_l[buf][w * 512]);
        gload16(Vh_g + voff, &Vs_h[buf][w * 512]);
        gload16(Vl_g + voff, &Vs_l[buf][w * 512]);
    };

    int qts[2];
    qts[0] = 15 - bx;   // heavy
    qts[1] = bx;        // light
#pragma unroll 1
    for (int qi = 0; qi < 2; qi++) {
        int qt = qts[qi];
        int q0 = qt * 128;
        int qrow_base = q0 + w * 16;

        short8 qfh[2], qfl[2];
        {
            size_t base = bhq + (size_t)(qrow_base + r15) * 64 + hq * 8;
            qfh[0] = *(const short8*)(Qh_g + base);
            qfh[1] = *(const short8*)(Qh_g + base + 32);
            qfl[0] = *(const short8*)(Ql_g + base);
            qfl[1] = *(const short8*)(Ql_g + base + 32);
        }

        floatx4 O[4];
        float m_[4], l_[4];
#pragma unroll
        for (int j = 0; j < 4; j++) O[j] = (floatx4)0.0f;
#pragma unroll
        for (int r = 0; r < 4; r++) { m_[r] = -INFINITY; l_[r] = 0.0f; }

        int ktmax = 2 * qt + 1;      // >= 1 always
        STAGE_KV(0, 0);
        STAGE_KV(1, 1);
#pragma unroll 1
        for (int kt = 0; kt <= ktmax; kt++) {
            int k0 = kt * 64;
            if (kt < ktmax) WAITV(4); else WAITV(0);
            SB0();
            __builtin_amdgcn_s_barrier();
            SB0();
            if (kt + 2 <= ktmax) STAGE_KV((kt + 2) % 3, kt + 2);

            if (k0 > qrow_base + 15) continue;   // fully masked for this wave
            bool needmask = (k0 + 63 > qrow_base);

            int cur = kt % 3;
            const short8* fKh = (const short8*)&Ks_h[cur][0];
            const short8* fKl = (const short8*)&Ks_l[cur][0];
            const short8* fVh = (const short8*)&Vs_h[cur][0];
            const short8* fVl = (const short8*)&Vs_l[cur][0];

            floatx4 S[4];
            __builtin_amdgcn_s_setprio(1);
#pragma unroll
            for (int j = 0; j < 4; j++) {
                short8 kh0 = fKh[(j * 2 + 0) * 64 + lane];
                short8 kh1 = fKh[(j * 2 + 1) * 64 + lane];
                short8 kl0 = fKl[(j * 2 + 0) * 64 + lane];
                short8 kl1 = fKl[(j * 2 + 1) * 64 + lane];
                floatx4 a = (floatx4)0.0f;
                a = __builtin_amdgcn_mfma_f32_16x16x32_bf16(qfh[0], kh0, a, 0, 0, 0);
                a = __builtin_amdgcn_mfma_f32_16x16x32_bf16(qfh[1], kh1, a, 0, 0, 0);
                a = __builtin_amdgcn_mfma_f32_16x16x32_bf16(qfh[0], kl0, a, 0, 0, 0);
                a = __builtin_amdgcn_mfma_f32_16x16x32_bf16(qfh[1], kl1, a, 0, 0, 0);
                a = __builtin_amdgcn_mfma_f32_16x16x32_bf16(qfl[0], kh0, a, 0, 0, 0);
                a = __builtin_amdgcn_mfma_f32_16x16x32_bf16(qfl[1], kh1, a, 0, 0, 0);
                S[j] = a;
            }
            __builtin_amdgcn_s_setprio(0);

#pragma unroll
            for (int j = 0; j < 4; j++)
#pragma unroll
                for (int r = 0; r < 4; r++) {
                    float v = S[j][r] * 0.125f;
                    if (needmask && (k0 + j * 16 + r15) > (qrow_base + hq * 4 + r)) v = -INFINITY;
                    S[j][r] = v;
                }

            float alpha[4];
#pragma unroll
            for (int r = 0; r < 4; r++) {
                float mt = fmaxf(fmaxf(S[0][r], S[1][r]), fmaxf(S[2][r], S[3][r]));
#pragma unroll
                for (int off = 1; off < 16; off <<= 1) mt = fmaxf(mt, __shfl_xor(mt, off));
                float mn = fmaxf(m_[r], mt);
                alpha[r] = __expf(m_[r] - mn);
                m_[r] = mn;
            }
            float rowsum[4] = {0.f, 0.f, 0.f, 0.f};
#pragma unroll
            for (int j = 0; j < 4; j++)
#pragma unroll
                for (int r = 0; r < 4; r++) {
                    float p = __expf(S[j][r] - m_[r]);
                    S[j][r] = p;
                    rowsum[r] += p;
                }
#pragma unroll
            for (int r = 0; r < 4; r++) {
#pragma unroll
                for (int off = 1; off < 16; off <<= 1) rowsum[r] += __shfl_xor(rowsum[r], off);
                l_[r] = l_[r] * alpha[r] + rowsum[r];
            }
#pragma unroll
            for (int jd = 0; jd < 4; jd++)
#pragma unroll
                for (int r = 0; r < 4; r++) O[jd][r] *= alpha[r];

            // P (D-layout) -> wave-private LDS (A-layout, XOR-swizzled)
            char* pw0 = (char*)&P_s[w][0][0];
            char* pw1 = (char*)&P_s[w][1][0];
#pragma unroll
            for (int j = 0; j < 4; j++)
#pragma unroll
                for (int r = 0; r < 4; r++) {
                    int prow = hq * 4 + r;
                    unsigned byte = (unsigned)(prow * 128 + (j * 16 + r15) * 2) ^ ((prow & 7) << 4);
                    unsigned short ph, pl;
                    splitf(S[j][r], ph, pl);
                    *(unsigned short*)(pw0 + byte) = ph;
                    *(unsigned short*)(pw1 + byte) = pl;
                }
            short8 pah[2], pal[2];
#pragma unroll
            for (int c = 0; c < 2; c++) {
                unsigned byte = (unsigned)(r15 * 128 + c * 64 + hq * 16) ^ ((r15 & 7) << 4);
                pah[c] = *(const short8*)(pw0 + byte);
                pal[c] = *(const short8*)(pw1 + byte);
            }

            __builtin_amdgcn_s_setprio(1);
#pragma unroll
            for (int jd = 0; jd < 4; jd++) {
                short8 vh0 = fVh[(jd * 2 + 0) * 64 + lane];
                short8 vh1 = fVh[(jd * 2 + 1) * 64 + lane];
                short8 vl0 = fVl[(jd * 2 + 0) * 64 + lane];
                short8 vl1 = fVl[(jd * 2 + 1) * 64 + lane];
                floatx4 a = O[jd];
                a = __builtin_amdgcn_mfma_f32_16x16x32_bf16(pah[0], vh0, a, 0, 0, 0);
                a = __builtin_amdgcn_mfma_f32_16x16x32_bf16(pah[1], vh1, a, 0, 0, 0);
                a = __builtin_amdgcn_mfma_f32_16x16x32_bf16(pah[0], vl0, a, 0, 0, 0);
                a = __builtin_amdgcn_mfma_f32_16x16x32_bf16(pah[1], vl1, a, 0, 0, 0);
                a = __builtin_amdgcn_mfma_f32_16x16x32_bf16(pal[0], vh0, a, 0, 0, 0);
                a = __builtin_amdgcn_mfma_f32_16x16x32_bf16(pal[1], vh1, a, 0, 0, 0);
                O[jd] = a;
            }
            __builtin_amdgcn_s_setprio(0);
        }

        // normalize + write y hi/lo
        float inv[4];
#pragma unroll
        for (int r = 0; r < 4; r++) inv[r] = 1.0f / l_[r];
#pragma unroll
        for (int jd = 0; jd < 4; jd++)
#pragma unroll
            for (int r = 0; r < 4; r++) {
                int t   = q0 + w * 16 + hq * 4 + r;
                int col = h * 64 + jd * 16 + r15;
                float v = O[jd][r] * inv[r];
                unsigned short hh, ll;
                splitf(v, hh, ll);
                size_t o = ((size_t)b * 2048 + t) * 1024 + col;
                yh[o] = hh;
                yl[o] = ll;
            }
        __syncthreads();   // full drain before next Q-tile reuses buffers
    }
}

// ---------------------------------------------------------------------------
extern "C" void kernel_launch(void* const* d_in, const int* in_sizes, int n_in,
                              void* d_out, int out_size, void* d_ws, size_t ws_size,
                              hipStream_t stream) {
    const float* x        = (const float*)d_in[0];
    const float* w_attn   = (const float*)d_in[1];
    const float* w_proj   = (const float*)d_in[2];
    const float* w_fc     = (const float*)d_in[3];
    const float* w_fcproj = (const float*)d_in[4];
    const float* ln1_w    = (const float*)d_in[5];
    const float* ln1_b    = (const float*)d_in[6];
    const float* ln2_w    = (const float*)d_in[7];
    const float* ln2_b    = (const float*)d_in[8];
    float* out = (float*)d_out;

    char* ws = (char*)d_ws;
    const size_t MB = 1048576;
    unsigned short* Qh   = (unsigned short*)(ws + 0 * MB);    // 8 MB each
    unsigned short* Ql   = (unsigned short*)(ws + 8 * MB);
    unsigned short* Kh   = (unsigned short*)(ws + 16 * MB);
    unsigned short* Kl   = (unsigned short*)(ws + 24 * MB);
    unsigned short* Vth  = (unsigned short*)(ws + 32 * MB);
    unsigned short* Vtl  = (unsigned short*)(ws + 40 * MB);
    unsigned short* acth = (unsigned short*)(ws + 0 * MB);    // 32 MB, reuses Q/K (dead)
    unsigned short* actl = (unsigned short*)(ws + 32 * MB);   // 32 MB, reuses Vt (dead)
    float*          x1   = (float*)(ws + 64 * MB);            // 16 MB
    unsigned short* ln_h = (unsigned short*)(ws + 80 * MB);   // 8 MB
    unsigned short* ln_l = (unsigned short*)(ws + 88 * MB);
    unsigned short* yb_h = (unsigned short*)(ws + 96 * MB);   // 8 MB
    unsigned short* yb_l = (unsigned short*)(ws + 104 * MB);
    unsigned short* wat_h  = (unsigned short*)(ws + 112 * MB);  // 6 MB
    unsigned short* wat_l  = (unsigned short*)(ws + 118 * MB);
    unsigned short* wpt_h  = (unsigned short*)(ws + 124 * MB);  // 2 MB
    unsigned short* wpt_l  = (unsigned short*)(ws + 126 * MB);
    unsigned short* wft_h  = (unsigned short*)(ws + 128 * MB);  // 8 MB
    unsigned short* wft_l  = (unsigned short*)(ws + 136 * MB);
    unsigned short* wfpt_h = (unsigned short*)(ws + 144 * MB);  // 8 MB
    unsigned short* wfpt_l = (unsigned short*)(ws + 152 * MB);  // ends 160 MB
    // split-K partials (written after ln/yb/wat/wpt/wft are dead)
    float* part0 = (float*)(ws +  80 * MB);   // 16 MB each
    float* part1 = (float*)(ws +  96 * MB);
    float* part2 = (float*)(ws + 112 * MB);
    float* part3 = (float*)(ws + 128 * MB);

    // weight convert+transpose
    wtrans_kernel<<<dim3(48, 16), 256, 0, stream>>>(w_attn,   wat_h,  wat_l,  1024, 3072);
    wtrans_kernel<<<dim3(16, 16), 256, 0, stream>>>(w_proj,   wpt_h,  wpt_l,  1024, 1024);
    wtrans_kernel<<<dim3(64, 16), 256, 0, stream>>>(w_fc,     wft_h,  wft_l,  1024, 4096);
    wtrans_kernel<<<dim3(16, 64), 256, 0, stream>>>(w_fcproj, wfpt_h, wfpt_l, 4096, 1024);

    // 1. ln1(x)
    ln_kernel<<<M_, 256, 0, stream>>>(x, ln1_w, ln1_b, ln_h, ln_l);
    // 2. qkv GEMM (256x128) with scatter epilogue -> Q,K [B,H,T,64]; V^T [B,H,64,T]
    gemm_px<3><<<dim3(24, 16), 512, 0, stream>>>(
        ln_h, ln_l, wat_h, wat_l, nullptr,
        Qh, Ql, Kh, Kl, Vth, Vtl, 3072, 1024, 1024);
    // 3. balanced pipelined MFMA flash attention -> yb hi/lo
    attn_mfma<<<dim3(8, 32), 512, 0, stream>>>(Qh, Ql, Kh, Kl, Vth, Vtl, yb_h, yb_l);
    // 4. x1 = yb @ w_proj + x   (128^2 pipelined)
    mfma_gemm_proj<<<dim3(8, 32), 256, 0, stream>>>(
        yb_h, yb_l, wpt_h, wpt_l, x, x1, 1024, 1024, 1024);
    // 5. ln2(x1)
    ln_kernel<<<M_, 256, 0, stream>>>(x1, ln2_w, ln2_b, ln_h, ln_l);
    // 6. act = gelu(ln2 @ w_fc)  (256x128)
    gemm_px<2><<<dim3(32, 16), 512, 0, stream>>>(
        ln_h, ln_l, wft_h, wft_l, nullptr,
        acth, actl, nullptr, nullptr, nullptr, nullptr, 4096, 1024, 1024);
    // 7. split-K=4 partials = act @ w_fcproj slices  (256x128)
    gemm_px<0><<<dim3(8, 16, 4), 512, 0, stream>>>(
        acth, actl, wfpt_h, wfpt_l, part0,
        nullptr, nullptr, nullptr, nullptr, nullptr, nullptr, 1024, 1024, 4096);
    // 8. out = part0..3 + x1
    combine4_kernel<<<4096, 256, 0, stream>>>(part0, part1, part2, part3, x1, out);
}

// Round 9
// 778.810 us; speedup vs baseline: 1.0108x; 1.0108x over previous
//
#include <hip/hip_runtime.h>
#include <math.h>

#define B_   2
#define T_   2048
#define C_   1024
#define H_   16
#define HD_  64
#define M_   (B_ * T_)   // 4096

typedef __attribute__((ext_vector_type(8))) short short8;
typedef __attribute__((ext_vector_type(4))) float floatx4;
typedef __attribute__((ext_vector_type(8))) unsigned short ushort8v;

#define WAITV(N) asm volatile("s_waitcnt vmcnt(" #N ")" ::: "memory")
#define SB0()    __builtin_amdgcn_sched_barrier(0)

// split fp32 -> bf16 hi (RNE) + bf16 lo (RNE of remainder)
__device__ __forceinline__ void splitf(float x, unsigned short& h, unsigned short& l) {
    unsigned u  = __float_as_uint(x);
    unsigned hr = (u + 0x7fffu + ((u >> 16) & 1u)) >> 16;
    h = (unsigned short)hr;
    float r = x - __uint_as_float(hr << 16);
    unsigned ur = __float_as_uint(r);
    l = (unsigned short)((ur + 0x7fffu + ((ur >> 16) & 1u)) >> 16);
}

__device__ __forceinline__ void gload16(const void* g, void* l) {
    __builtin_amdgcn_global_load_lds(
        (const __attribute__((address_space(1))) unsigned int*)g,
        (__attribute__((address_space(3))) unsigned int*)l, 16, 0, 0);
}

__device__ __forceinline__ float gelu_f(float x) {
    const float c = 0.7978845608028654f;  // sqrt(2/pi)
    float x3 = x * x * x;
    return 0.5f * x * (1.0f + tanhf(c * (x + 0.044715f * x3)));
}

// ---------------------------------------------------------------------------
// LayerNorm: one block per row, outputs hi/lo bf16.
// ---------------------------------------------------------------------------
__global__ __launch_bounds__(256) void ln_kernel(const float* __restrict__ x,
                                                 const float* __restrict__ w,
                                                 const float* __restrict__ b,
                                                 unsigned short* __restrict__ oh,
                                                 unsigned short* __restrict__ ol) {
    int row = blockIdx.x;
    int t   = threadIdx.x;
    const float4* xr = (const float4*)(x + (size_t)row * C_);
    float4 v = xr[t];
    float s  = v.x + v.y + v.z + v.w;
    float sq = v.x * v.x + v.y * v.y + v.z * v.z + v.w * v.w;
#pragma unroll
    for (int off = 32; off > 0; off >>= 1) {
        s  += __shfl_down(s,  off);
        sq += __shfl_down(sq, off);
    }
    __shared__ float ss[4], ssq[4];
    int wid = t >> 6, lane = t & 63;
    if (lane == 0) { ss[wid] = s; ssq[wid] = sq; }
    __syncthreads();
    float S  = ss[0] + ss[1] + ss[2] + ss[3];
    float SQ = ssq[0] + ssq[1] + ssq[2] + ssq[3];
    float mu   = S * (1.0f / C_);
    float var  = SQ * (1.0f / C_) - mu * mu;
    float rstd = rsqrtf(var + 1e-5f);
    float4 wv = ((const float4*)w)[t];
    float4 bv = ((const float4*)b)[t];
    float o0 = (v.x - mu) * rstd * wv.x + bv.x;
    float o1 = (v.y - mu) * rstd * wv.y + bv.y;
    float o2 = (v.z - mu) * rstd * wv.z + bv.z;
    float o3 = (v.w - mu) * rstd * wv.w + bv.w;
    ushort4 hv, lv;
    splitf(o0, hv.x, lv.x); splitf(o1, hv.y, lv.y);
    splitf(o2, hv.z, lv.z); splitf(o3, hv.w, lv.w);
    *(ushort4*)(oh + (size_t)row * C_ + t * 4) = hv;
    *(ushort4*)(ol + (size_t)row * C_ + t * 4) = lv;
}

// ---------------------------------------------------------------------------
// Merged weight convert+transpose for all 4 weights (segmented grid).
// W [K][N] f32 -> Wt_hi/lo [N][K] bf16. 64x64 tiles, 3072 blocks total.
// ---------------------------------------------------------------------------
__global__ __launch_bounds__(256) void wtrans_all(
    const float* __restrict__ W0, unsigned short* __restrict__ th0, unsigned short* __restrict__ tl0,
    const float* __restrict__ W1, unsigned short* __restrict__ th1, unsigned short* __restrict__ tl1,
    const float* __restrict__ W2, unsigned short* __restrict__ th2, unsigned short* __restrict__ tl2,
    const float* __restrict__ W3, unsigned short* __restrict__ th3, unsigned short* __restrict__ tl3) {
    __shared__ unsigned int tile[64][65];  // hi | lo<<16
    int g = blockIdx.x;
    const float* W; unsigned short *th, *tl; int K, N, ntx, tid2;
    if (g < 768)       { W = W0; th = th0; tl = tl0; K = 1024; N = 3072; ntx = 48; tid2 = g; }
    else if (g < 1024) { W = W1; th = th1; tl = tl1; K = 1024; N = 1024; ntx = 16; tid2 = g - 768; }
    else if (g < 2048) { W = W2; th = th2; tl = tl2; K = 1024; N = 4096; ntx = 64; tid2 = g - 1024; }
    else               { W = W3; th = th3; tl = tl3; K = 4096; N = 1024; ntx = 16; tid2 = g - 2048; }
    int n0 = (tid2 % ntx) * 64, k0 = (tid2 / ntx) * 64;
    int t  = threadIdx.x;
    int tc = (t & 15) * 4, tr = t >> 4;
#pragma unroll
    for (int it = 0; it < 4; it++) {
        int kr = it * 16 + tr;
        float4 v = *(const float4*)(W + (size_t)(k0 + kr) * N + n0 + tc);
        unsigned short hh, ll;
        splitf(v.x, hh, ll); tile[kr][tc + 0] = (unsigned)hh | ((unsigned)ll << 16);
        splitf(v.y, hh, ll); tile[kr][tc + 1] = (unsigned)hh | ((unsigned)ll << 16);
        splitf(v.z, hh, ll); tile[kr][tc + 2] = (unsigned)hh | ((unsigned)ll << 16);
        splitf(v.w, hh, ll); tile[kr][tc + 3] = (unsigned)hh | ((unsigned)ll << 16);
    }
    __syncthreads();
    int nl = t >> 2, kc = (t & 3) * 16;
    ushort8v h0, h1, l0, l1;
#pragma unroll
    for (int e = 0; e < 8; e++) {
        unsigned u = tile[kc + e][nl];
        h0[e] = (unsigned short)(u & 0xffff); l0[e] = (unsigned short)(u >> 16);
    }
#pragma unroll
    for (int e = 0; e < 8; e++) {
        unsigned u = tile[kc + 8 + e][nl];
        h1[e] = (unsigned short)(u & 0xffff); l1[e] = (unsigned short)(u >> 16);
    }
    size_t o = (size_t)(n0 + nl) * K + k0 + kc;
    *(ushort8v*)(th + o)     = h0;
    *(ushort8v*)(th + o + 8) = h1;
    *(ushort8v*)(tl + o)     = l0;
    *(ushort8v*)(tl + o + 8) = l1;
}

// ---------------------------------------------------------------------------
// 128x128 split-bf16 MFMA GEMM, 2-phase prefetch (dbuf). proj: C = A@B + R.
// ---------------------------------------------------------------------------
__global__ __launch_bounds__(256) void mfma_gemm_proj(
    const unsigned short* __restrict__ Ah, const unsigned short* __restrict__ Al,
    const unsigned short* __restrict__ Bh, const unsigned short* __restrict__ Bl,
    const float* __restrict__ R, float* __restrict__ Cf,
    int N, int K, int Kstride) {
    __shared__ unsigned short lAh[2][4096], lAl[2][4096];
    __shared__ unsigned short lBh[2][4096], lBl[2][4096];   // 64 KB
    int tid = threadIdx.x, lane = tid & 63, w = tid >> 6;
    int wr = w >> 1, wc = w & 1;

    int nx = gridDim.x;
    int nwg = nx * gridDim.y;
    int bid = blockIdx.y * nx + blockIdx.x;
    int q8  = nwg >> 3;
    int swz = (bid & 7) * q8 + (bid >> 3);
    int bm = (swz / nx) * 128, bn = (swz % nx) * 128;

    int r15 = lane & 15, hq = lane >> 4;

    floatx4 acc[4][4];
#pragma unroll
    for (int i = 0; i < 4; i++)
#pragma unroll
        for (int j = 0; j < 4; j++) acc[i][j] = (floatx4)0.0f;

    auto STAGE = [&](int buf, int k0) {
#pragma unroll
        for (int s = 0; s < 2; s++) {
            int sf = 2 * w + s;
            size_t arow = (size_t)(bm + sf * 16 + r15) * Kstride + k0 + hq * 8;
            size_t brow = (size_t)(bn + sf * 16 + r15) * Kstride + k0 + hq * 8;
            gload16(Ah + arow, &lAh[buf][sf * 512]);
            gload16(Al + arow, &lAl[buf][sf * 512]);
            gload16(Bh + brow, &lBh[buf][sf * 512]);
            gload16(Bl + brow, &lBl[buf][sf * 512]);
        }
    };

    STAGE(0, 0);
    __syncthreads();
    int cur = 0;
    int nt = K / 32;
    for (int t = 0; t < nt; t++) {
        if (t + 1 < nt) STAGE(cur ^ 1, (t + 1) * 32);
        const short8* fAh = (const short8*)&lAh[cur][0];
        const short8* fAl = (const short8*)&lAl[cur][0];
        const short8* fBh = (const short8*)&lBh[cur][0];
        const short8* fBl = (const short8*)&lBl[cur][0];
        short8 a_h[4], a_l[4], b_h[4], b_l[4];
#pragma unroll
        for (int i = 0; i < 4; i++) {
            a_h[i] = fAh[(wr * 4 + i) * 64 + lane];
            a_l[i] = fAl[(wr * 4 + i) * 64 + lane];
            b_h[i] = fBh[(wc * 4 + i) * 64 + lane];
            b_l[i] = fBl[(wc * 4 + i) * 64 + lane];
        }
        __builtin_amdgcn_s_setprio(1);
#pragma unroll
        for (int i = 0; i < 4; i++)
#pragma unroll
            for (int j = 0; j < 4; j++) {
                acc[i][j] = __builtin_amdgcn_mfma_f32_16x16x32_bf16(a_h[i], b_h[j], acc[i][j], 0, 0, 0);
                acc[i][j] = __builtin_amdgcn_mfma_f32_16x16x32_bf16(a_h[i], b_l[j], acc[i][j], 0, 0, 0);
                acc[i][j] = __builtin_amdgcn_mfma_f32_16x16x32_bf16(a_l[i], b_h[j], acc[i][j], 0, 0, 0);
            }
        __builtin_amdgcn_s_setprio(0);
        __syncthreads();
        cur ^= 1;
    }

    int er = hq * 4, ec = r15;
#pragma unroll
    for (int i = 0; i < 4; i++)
#pragma unroll
        for (int j = 0; j < 4; j++) {
            int row0 = bm + wr * 64 + i * 16 + er;
            int col  = bn + wc * 64 + j * 16 + ec;
#pragma unroll
            for (int r = 0; r < 4; r++) {
                int row = row0 + r;
                Cf[(size_t)row * N + col] = acc[i][j][r] + R[(size_t)row * N + col];
            }
        }
}

// ---------------------------------------------------------------------------
// 256x256 split-bf16 MFMA GEMM, 2-phase prefetch, 8 waves (2Mx4N), BK=32,
// 128 KB double-buffered LDS. EPI: 0 = split-K partial f32 store;
// 2 = gelu -> hi/lo bf16; 3 = qkv scatter.
// ---------------------------------------------------------------------------
template <int EPI>
__global__ __launch_bounds__(512, 2) void mfma_gemm256(
    const unsigned short* __restrict__ Ah, const unsigned short* __restrict__ Al,
    const unsigned short* __restrict__ Bh, const unsigned short* __restrict__ Bl,
    float* __restrict__ Cf,
    unsigned short* __restrict__ Ch, unsigned short* __restrict__ Cl,
    unsigned short* __restrict__ K2h, unsigned short* __restrict__ K2l,
    unsigned short* __restrict__ V2h, unsigned short* __restrict__ V2l,
    int N, int K, int Kstride) {
    __shared__ unsigned short lAh[2][8192], lAl[2][8192];   // 256 rows x 32 k
    __shared__ unsigned short lBh[2][8192], lBl[2][8192];   // 128 KB total
    int tid = threadIdx.x, lane = tid & 63, w = tid >> 6;   // w in 0..7
    int wr = w >> 2, wc = w & 3;                            // 2M x 4N waves

    int nx = gridDim.x;
    int nwg = nx * gridDim.y;
    int bid = blockIdx.y * nx + blockIdx.x;
    int q8  = nwg >> 3;
    int swz = (bid & 7) * q8 + (bid >> 3);
    int bm = (swz / nx) * 256, bn = (swz % nx) * 256;

    int kb = blockIdx.z * K;
    if (EPI == 0) Cf += (size_t)blockIdx.z * (size_t)gridDim.y * 256 * N;

    int r15 = lane & 15, hq = lane >> 4;

    floatx4 acc[8][4];
#pragma unroll
    for (int i = 0; i < 8; i++)
#pragma unroll
        for (int j = 0; j < 4; j++) acc[i][j] = (floatx4)0.0f;

    auto STAGE = [&](int buf, int k0) {
#pragma unroll
        for (int s = 0; s < 2; s++) {
            int sf = 2 * w + s;   // 16 subtiles of 16 rows each
            size_t arow = (size_t)(bm + sf * 16 + r15) * Kstride + kb + k0 + hq * 8;
            size_t brow = (size_t)(bn + sf * 16 + r15) * Kstride + kb + k0 + hq * 8;
            gload16(Ah + arow, &lAh[buf][sf * 512]);
            gload16(Al + arow, &lAl[buf][sf * 512]);
            gload16(Bh + brow, &lBh[buf][sf * 512]);
            gload16(Bl + brow, &lBl[buf][sf * 512]);
        }
    };

    STAGE(0, 0);
    __syncthreads();
    int cur = 0;
    int nt = K / 32;
    for (int t = 0; t < nt; t++) {
        if (t + 1 < nt) STAGE(cur ^ 1, (t + 1) * 32);
        const short8* fAh = (const short8*)&lAh[cur][0];
        const short8* fAl = (const short8*)&lAl[cur][0];
        const short8* fBh = (const short8*)&lBh[cur][0];
        const short8* fBl = (const short8*)&lBl[cur][0];
        short8 b_h[4], b_l[4];
#pragma unroll
        for (int j = 0; j < 4; j++) {
            b_h[j] = fBh[(wc * 4 + j) * 64 + lane];
            b_l[j] = fBl[(wc * 4 + j) * 64 + lane];
        }
        __builtin_amdgcn_s_setprio(1);
#pragma unroll
        for (int i = 0; i < 8; i++) {
            short8 a_h = fAh[(wr * 8 + i) * 64 + lane];
            short8 a_l = fAl[(wr * 8 + i) * 64 + lane];
#pragma unroll
            for (int j = 0; j < 4; j++) {
                acc[i][j] = __builtin_amdgcn_mfma_f32_16x16x32_bf16(a_h, b_h[j], acc[i][j], 0, 0, 0);
                acc[i][j] = __builtin_amdgcn_mfma_f32_16x16x32_bf16(a_h, b_l[j], acc[i][j], 0, 0, 0);
                acc[i][j] = __builtin_amdgcn_mfma_f32_16x16x32_bf16(a_l, b_h[j], acc[i][j], 0, 0, 0);
            }
        }
        __builtin_amdgcn_s_setprio(0);
        __syncthreads();
        cur ^= 1;
    }

    int er = hq * 4, ec = r15;
#pragma unroll
    for (int i = 0; i < 8; i++) {
#pragma unroll
        for (int j = 0; j < 4; j++) {
            int row0 = bm + wr * 128 + i * 16 + er;
            int col  = bn + wc * 64 + j * 16 + ec;
            if (EPI == 0) {
#pragma unroll
                for (int r = 0; r < 4; r++)
                    Cf[(size_t)(row0 + r) * N + col] = acc[i][j][r];
            } else if (EPI == 2) {
#pragma unroll
                for (int r = 0; r < 4; r++) {
                    int row = row0 + r;
                    float g = gelu_f(acc[i][j][r]);
                    unsigned short hh, ll;
                    splitf(g, hh, ll);
                    Ch[(size_t)row * N + col] = hh;
                    Cl[(size_t)row * N + col] = ll;
                }
            } else {  // EPI == 3: qkv scatter
                int region = bn >> 10;   // uniform per block (256-multiple bn)
                int b_ = row0 >> 11;
                int h_ = (col >> 6) & 15;
                int d_ = col & 63;
                size_t bh_ = (size_t)(b_ * 16 + h_);
                if (region == 2) {
                    ushort4 hv, lv;
                    splitf(acc[i][j][0], hv.x, lv.x);
                    splitf(acc[i][j][1], hv.y, lv.y);
                    splitf(acc[i][j][2], hv.z, lv.z);
                    splitf(acc[i][j][3], hv.w, lv.w);
                    size_t o = (bh_ * 64 + d_) * 2048 + (row0 & 2047);
                    *(ushort4*)(V2h + o) = hv;
                    *(ushort4*)(V2l + o) = lv;
                } else {
                    unsigned short* dh = (region == 0) ? Ch : K2h;
                    unsigned short* dl = (region == 0) ? Cl : K2l;
#pragma unroll
                    for (int r = 0; r < 4; r++) {
                        int t_ = (row0 + r) & 2047;
                        unsigned short hh, ll;
                        splitf(acc[i][j][r], hh, ll);
                        size_t o = (bh_ * 2048 + t_) * 64 + d_;
                        dh[o] = hh;
                        dl[o] = ll;
                    }
                }
            }
        }
    }
}

// ---------------------------------------------------------------------------
// split-K=4 combine: out = p0+p1+p2+p3 + residual
// ---------------------------------------------------------------------------
__global__ __launch_bounds__(256) void combine4_kernel(const float* __restrict__ p0,
                                                       const float* __restrict__ p1,
                                                       const float* __restrict__ p2,
                                                       const float* __restrict__ p3,
                                                       const float* __restrict__ r,
                                                       float* __restrict__ out) {
    int i = blockIdx.x * 256 + threadIdx.x;
    float4 a = ((const float4*)p0)[i];
    float4 b = ((const float4*)p1)[i];
    float4 c = ((const float4*)p2)[i];
    float4 d = ((const float4*)p3)[i];
    float4 e = ((const float4*)r)[i];
    float4 o;
    o.x = a.x + b.x + c.x + d.x + e.x;
    o.y = a.y + b.y + c.y + d.y + e.y;
    o.z = a.z + b.z + c.z + d.z + e.z;
    o.w = a.w + b.w + c.w + d.w + e.w;
    ((float4*)out)[i] = o;
}

// ---------------------------------------------------------------------------
// Split-bf16 MFMA flash attention (causal), work-balanced + pipelined.
// Each block handles TWO Q-tiles of 128 rows: qt = 15-bx (heavy) then bx
// (light) -> uniform 34 KV-iters/block. Grid 8 x 32 = 256 blocks = 1/CU.
// K/V triple-buffered in LDS, counted vmcnt(4), one barrier per KV-iter.
// ---------------------------------------------------------------------------
__global__ __launch_bounds__(512) void attn_mfma(
    const unsigned short* __restrict__ Qh_g, const unsigned short* __restrict__ Ql_g,
    const unsigned short* __restrict__ Kh_g, const unsigned short* __restrict__ Kl_g,
    const unsigned short* __restrict__ Vh_g, const unsigned short* __restrict__ Vl_g,
    unsigned short* __restrict__ yh, unsigned short* __restrict__ yl) {
    __shared__ unsigned short Ks_h[3][4096], Ks_l[3][4096];
    __shared__ unsigned short Vs_h[3][4096], Vs_l[3][4096];   // 96 KB
    __shared__ unsigned short P_s[8][2][1024];                // 32 KB

    int bx  = blockIdx.x;            // 0..7
    int bh  = blockIdx.y;
    int b   = bh >> 4, h = bh & 15;
    int tid = threadIdx.x, lane = tid & 63, w = tid >> 6;
    int r15 = lane & 15, hq = lane >> 4;
    size_t bhq = (size_t)bh * (2048 * 64);
    size_t bhv = (size_t)bh * (64 * 2048);
    int srb = w >> 1, scb = w & 1;

    auto STAGE_KV = [&](int buf, int kt) {
        int k0 = kt * 64;
        size_t koff = bhq + (size_t)(k0 + srb * 16 + r15) * 64 + scb * 32 + hq * 8;
        size_t voff = bhv + (size_t)(srb * 16 + r15) * 2048 + k0 + scb * 32 + hq * 8;
        gload16(Kh_g + koff, &Ks_h[buf][w * 512]);
        gload16(Kl_g + koff, &Ks_l[buf][w * 512]);
        gload16(Vh_g + voff, &Vs_h[buf][w * 512]);
        gload16(Vl_g + voff, &Vs_l[buf][w * 512]);
    };

    int qts[2];
    qts[0] = 15 - bx;   // heavy
    qts[1] = bx;        // light
#pragma unroll 1
    for (int qi = 0; qi < 2; qi++) {
        int qt = qts[qi];
        int q0 = qt * 128;
        int qrow_base = q0 + w * 16;

        short8 qfh[2], qfl[2];
        {
            size_t base = bhq + (size_t)(qrow_base + r15) * 64 + hq * 8;
            qfh[0] = *(const short8*)(Qh_g + base);
            qfh[1] = *(const short8*)(Qh_g + base + 32);
            qfl[0] = *(const short8*)(Ql_g + base);
            qfl[1] = *(const short8*)(Ql_g + base + 32);
        }

        floatx4 O[4];
        float m_[4], l_[4];
#pragma unroll
        for (int j = 0; j < 4; j++) O[j] = (floatx4)0.0f;
#pragma unroll
        for (int r = 0; r < 4; r++) { m_[r] = -INFINITY; l_[r] = 0.0f; }

        int ktmax = 2 * qt + 1;      // >= 1 always
        STAGE_KV(0, 0);
        STAGE_KV(1, 1);
#pragma unroll 1
        for (int kt = 0; kt <= ktmax; kt++) {
            int k0 = kt * 64;
            if (kt < ktmax) WAITV(4); else WAITV(0);
            SB0();
            __builtin_amdgcn_s_barrier();
            SB0();
            if (kt + 2 <= ktmax) STAGE_KV((kt + 2) % 3, kt + 2);

            if (k0 > qrow_base + 15) continue;   // fully masked for this wave
            bool needmask = (k0 + 63 > qrow_base);

            int cur = kt % 3;
            const short8* fKh = (const short8*)&Ks_h[cur][0];
            const short8* fKl = (const short8*)&Ks_l[cur][0];
            const short8* fVh = (const short8*)&Vs_h[cur][0];
            const short8* fVl = (const short8*)&Vs_l[cur][0];

            floatx4 S[4];
            __builtin_amdgcn_s_setprio(1);
#pragma unroll
            for (int j = 0; j < 4; j++) {
                short8 kh0 = fKh[(j * 2 + 0) * 64 + lane];
                short8 kh1 = fKh[(j * 2 + 1) * 64 + lane];
                short8 kl0 = fKl[(j * 2 + 0) * 64 + lane];
                short8 kl1 = fKl[(j * 2 + 1) * 64 + lane];
                floatx4 a = (floatx4)0.0f;
                a = __builtin_amdgcn_mfma_f32_16x16x32_bf16(qfh[0], kh0, a, 0, 0, 0);
                a = __builtin_amdgcn_mfma_f32_16x16x32_bf16(qfh[1], kh1, a, 0, 0, 0);
                a = __builtin_amdgcn_mfma_f32_16x16x32_bf16(qfh[0], kl0, a, 0, 0, 0);
                a = __builtin_amdgcn_mfma_f32_16x16x32_bf16(qfh[1], kl1, a, 0, 0, 0);
                a = __builtin_amdgcn_mfma_f32_16x16x32_bf16(qfl[0], kh0, a, 0, 0, 0);
                a = __builtin_amdgcn_mfma_f32_16x16x32_bf16(qfl[1], kh1, a, 0, 0, 0);
                S[j] = a;
            }
            __builtin_amdgcn_s_setprio(0);

#pragma unroll
            for (int j = 0; j < 4; j++)
#pragma unroll
                for (int r = 0; r < 4; r++) {
                    float v = S[j][r] * 0.125f;
                    if (needmask && (k0 + j * 16 + r15) > (qrow_base + hq * 4 + r)) v = -INFINITY;
                    S[j][r] = v;
                }

            float alpha[4];
#pragma unroll
            for (int r = 0; r < 4; r++) {
                float mt = fmaxf(fmaxf(S[0][r], S[1][r]), fmaxf(S[2][r], S[3][r]));
#pragma unroll
                for (int off = 1; off < 16; off <<= 1) mt = fmaxf(mt, __shfl_xor(mt, off));
                float mn = fmaxf(m_[r], mt);
                alpha[r] = __expf(m_[r] - mn);
                m_[r] = mn;
            }
            float rowsum[4] = {0.f, 0.f, 0.f, 0.f};
#pragma unroll
            for (int j = 0; j < 4; j++)
#pragma unroll
                for (int r = 0; r < 4; r++) {
                    float p = __expf(S[j][r] - m_[r]);
                    S[j][r] = p;
                    rowsum[r] += p;
                }
#pragma unroll
            for (int r = 0; r < 4; r++) {
#pragma unroll
                for (int off = 1; off < 16; off <<= 1) rowsum[r] += __shfl_xor(rowsum[r], off);
                l_[r] = l_[r] * alpha[r] + rowsum[r];
            }
#pragma unroll
            for (int jd = 0; jd < 4; jd++)
#pragma unroll
                for (int r = 0; r < 4; r++) O[jd][r] *= alpha[r];

            // P (D-layout) -> wave-private LDS (A-layout, XOR-swizzled)
            char* pw0 = (char*)&P_s[w][0][0];
            char* pw1 = (char*)&P_s[w][1][0];
#pragma unroll
            for (int j = 0; j < 4; j++)
#pragma unroll
                for (int r = 0; r < 4; r++) {
                    int prow = hq * 4 + r;
                    unsigned byte = (unsigned)(prow * 128 + (j * 16 + r15) * 2) ^ ((prow & 7) << 4);
                    unsigned short ph, pl;
                    splitf(S[j][r], ph, pl);
                    *(unsigned short*)(pw0 + byte) = ph;
                    *(unsigned short*)(pw1 + byte) = pl;
                }
            short8 pah[2], pal[2];
#pragma unroll
            for (int c = 0; c < 2; c++) {
                unsigned byte = (unsigned)(r15 * 128 + c * 64 + hq * 16) ^ ((r15 & 7) << 4);
                pah[c] = *(const short8*)(pw0 + byte);
                pal[c] = *(const short8*)(pw1 + byte);
            }

            __builtin_amdgcn_s_setprio(1);
#pragma unroll
            for (int jd = 0; jd < 4; jd++) {
                short8 vh0 = fVh[(jd * 2 + 0) * 64 + lane];
                short8 vh1 = fVh[(jd * 2 + 1) * 64 + lane];
                short8 vl0 = fVl[(jd * 2 + 0) * 64 + lane];
                short8 vl1 = fVl[(jd * 2 + 1) * 64 + lane];
                floatx4 a = O[jd];
                a = __builtin_amdgcn_mfma_f32_16x16x32_bf16(pah[0], vh0, a, 0, 0, 0);
                a = __builtin_amdgcn_mfma_f32_16x16x32_bf16(pah[1], vh1, a, 0, 0, 0);
                a = __builtin_amdgcn_mfma_f32_16x16x32_bf16(pah[0], vl0, a, 0, 0, 0);
                a = __builtin_amdgcn_mfma_f32_16x16x32_bf16(pah[1], vl1, a, 0, 0, 0);
                a = __builtin_amdgcn_mfma_f32_16x16x32_bf16(pal[0], vh0, a, 0, 0, 0);
                a = __builtin_amdgcn_mfma_f32_16x16x32_bf16(pal[1], vh1, a, 0, 0, 0);
                O[jd] = a;
            }
            __builtin_amdgcn_s_setprio(0);
        }

        // normalize + write y hi/lo
        float inv[4];
#pragma unroll
        for (int r = 0; r < 4; r++) inv[r] = 1.0f / l_[r];
#pragma unroll
        for (int jd = 0; jd < 4; jd++)
#pragma unroll
            for (int r = 0; r < 4; r++) {
                int t   = q0 + w * 16 + hq * 4 + r;
                int col = h * 64 + jd * 16 + r15;
                float v = O[jd][r] * inv[r];
                unsigned short hh, ll;
                splitf(v, hh, ll);
                size_t o = ((size_t)b * 2048 + t) * 1024 + col;
                yh[o] = hh;
                yl[o] = ll;
            }
        __syncthreads();   // full drain before next Q-tile reuses buffers
    }
}

// ---------------------------------------------------------------------------
extern "C" void kernel_launch(void* const* d_in, const int* in_sizes, int n_in,
                              void* d_out, int out_size, void* d_ws, size_t ws_size,
                              hipStream_t stream) {
    const float* x        = (const float*)d_in[0];
    const float* w_attn   = (const float*)d_in[1];
    const float* w_proj   = (const float*)d_in[2];
    const float* w_fc     = (const float*)d_in[3];
    const float* w_fcproj = (const float*)d_in[4];
    const float* ln1_w    = (const float*)d_in[5];
    const float* ln1_b    = (const float*)d_in[6];
    const float* ln2_w    = (const float*)d_in[7];
    const float* ln2_b    = (const float*)d_in[8];
    float* out = (float*)d_out;

    char* ws = (char*)d_ws;
    const size_t MB = 1048576;
    unsigned short* Qh   = (unsigned short*)(ws + 0 * MB);    // 8 MB each
    unsigned short* Ql   = (unsigned short*)(ws + 8 * MB);
    unsigned short* Kh   = (unsigned short*)(ws + 16 * MB);
    unsigned short* Kl   = (unsigned short*)(ws + 24 * MB);
    unsigned short* Vth  = (unsigned short*)(ws + 32 * MB);
    unsigned short* Vtl  = (unsigned short*)(ws + 40 * MB);
    unsigned short* acth = (unsigned short*)(ws + 0 * MB);    // 32 MB, reuses Q/K (dead)
    unsigned short* actl = (unsigned short*)(ws + 32 * MB);   // 32 MB, reuses Vt (dead)
    float*          x1   = (float*)(ws + 64 * MB);            // 16 MB
    unsigned short* ln_h = (unsigned short*)(ws + 80 * MB);   // 8 MB
    unsigned short* ln_l = (unsigned short*)(ws + 88 * MB);
    unsigned short* yb_h = (unsigned short*)(ws + 96 * MB);   // 8 MB
    unsigned short* yb_l = (unsigned short*)(ws + 104 * MB);
    unsigned short* wat_h  = (unsigned short*)(ws + 112 * MB);  // 6 MB
    unsigned short* wat_l  = (unsigned short*)(ws + 118 * MB);
    unsigned short* wpt_h  = (unsigned short*)(ws + 124 * MB);  // 2 MB
    unsigned short* wpt_l  = (unsigned short*)(ws + 126 * MB);
    unsigned short* wft_h  = (unsigned short*)(ws + 128 * MB);  // 8 MB
    unsigned short* wft_l  = (unsigned short*)(ws + 136 * MB);
    unsigned short* wfpt_h = (unsigned short*)(ws + 144 * MB);  // 8 MB
    unsigned short* wfpt_l = (unsigned short*)(ws + 152 * MB);  // ends 160 MB
    // split-K partials (written after ln/yb/wat/wpt/wft are dead)
    float* part0 = (float*)(ws +  80 * MB);   // 16 MB each
    float* part1 = (float*)(ws +  96 * MB);
    float* part2 = (float*)(ws + 112 * MB);
    float* part3 = (float*)(ws + 128 * MB);

    // 0. merged weight convert+transpose (3072 tiles)
    wtrans_all<<<3072, 256, 0, stream>>>(
        w_attn,   wat_h,  wat_l,
        w_proj,   wpt_h,  wpt_l,
        w_fc,     wft_h,  wft_l,
        w_fcproj, wfpt_h, wfpt_l);

    // 1. ln1(x)
    ln_kernel<<<M_, 256, 0, stream>>>(x, ln1_w, ln1_b, ln_h, ln_l);
    // 2. qkv GEMM (256^2) with scatter epilogue -> Q,K [B,H,T,64]; V^T [B,H,64,T]
    mfma_gemm256<3><<<dim3(12, 16), 512, 0, stream>>>(
        ln_h, ln_l, wat_h, wat_l, nullptr,
        Qh, Ql, Kh, Kl, Vth, Vtl, 3072, 1024, 1024);
    // 3. balanced pipelined MFMA flash attention -> yb hi/lo
    attn_mfma<<<dim3(8, 32), 512, 0, stream>>>(Qh, Ql, Kh, Kl, Vth, Vtl, yb_h, yb_l);
    // 4. x1 = yb @ w_proj + x   (128^2 2-phase)
    mfma_gemm_proj<<<dim3(8, 32), 256, 0, stream>>>(
        yb_h, yb_l, wpt_h, wpt_l, x, x1, 1024, 1024, 1024);
    // 5. ln2(x1)
    ln_kernel<<<M_, 256, 0, stream>>>(x1, ln2_w, ln2_b, ln_h, ln_l);
    // 6. act = gelu(ln2 @ w_fc)  (256^2)
    mfma_gemm256<2><<<dim3(16, 16), 512, 0, stream>>>(
        ln_h, ln_l, wft_h, wft_l, nullptr,
        acth, actl, nullptr, nullptr, nullptr, nullptr, 4096, 1024, 1024);
    // 7. split-K=4 partials = act @ w_fcproj slices  (256^2)
    mfma_gemm256<0><<<dim3(4, 16, 4), 512, 0, stream>>>(
        acth, actl, wfpt_h, wfpt_l, part0,
        nullptr, nullptr, nullptr, nullptr, nullptr, nullptr, 1024, 1024, 4096);
    // 8. out = part0..3 + x1
    combine4_kernel<<<4096, 256, 0, stream>>>(part0, part1, part2, part3, x1, out);
}